// Round 7
// baseline (35.545 us; speedup 1.0000x reference)
//
#include <hip/hip_runtime.h>
#include <math.h>

// MozafariV3 forward collapses analytically:
//   counts[b, c] = (c1max_b > 0.01) ? T - clip(trunc((1 - c1max_b) * (T-1)), 0, T-1) : 0
//   with c1max_b = max_pixels|gabor_conv(x_b)| / (global_max + 1e-8)
//   preds[b] = argmax_c counts[b, :] = 0 (all classes tie; argmax picks first).
//
// R1: per-wave atomicMax onto 32 words serialized (314 us) — but RMW coherence OK.
// R2: full unroll -> 256 VGPR -> 106 MB scratch spill (60 us).
// R3: stale seg*1024 base -> half image unscanned.
// R4: two kernels, 16.4 us, launch-bound. PROVEN GOOD fallback.
// R5: fused, FAILED: (a) mod-ticket with poisoned counter selects a NON-last block
//     (0xAAAAAAAA % 1024 = 682 -> "finalizer" at arrival #342, races 682 blocks);
//     (b) relaxed agent load of pb can be served stale cross-XCD.
// R6: FAILED identically: fetch_or(p,0) is an idempotent RMW -> LLVM canonicalizes
//     it to the same atomic LOAD as R5 (lowerIdempotentRMWIntoFencedLoad).
// R7: (1) hipMemsetAsync zeroes the ticket counter every call (memset node is
//     graph-capturable) -> old==GRID-1 is the TRUE last arriver;
//     (2) publish per-batch max via signed-int fetch_max RMW (R1-proven coherent;
//     poison 0xAA is negative -> self-healing; idempotent across replays);
//     (3) finalizer reads via CAS with impossible expected (NaN bits) — cannot be
//     folded to a load; failed CAS returns the coherence-point value.

#define NPB 32   // blocks per batch; each block covers 4 rows (512 pixels)
#define NB  32   // batch
#define GRID (NB * NPB)   // 1024

__global__ __launch_bounds__(256) void fused_kernel(const float* __restrict__ x,
                                                    int* __restrict__ bmax,      // NB slots
                                                    unsigned* __restrict__ cnt,  // ticket
                                                    const int* __restrict__ Tin,
                                                    float* __restrict__ out,
                                                    int nC) {
    __shared__ float g[100];
    __shared__ double traw[100];
    __shared__ double mean4[4], nrm4[4];
    __shared__ float wmax[4];
    __shared__ int isLast;
    int tid = threadIdx.x;

    // ---- Gabor build (double precision; proven absmax 0) ----
    if (tid < 100) {
        int o = tid / 25, t = tid % 25, r = t / 5, c = t % 5;
        double theta = (double)o * M_PI / 4.0;
        double ct = cos(theta), st = sin(theta);
        double xx = (double)(c - 2), yy = (double)(r - 2);
        double xt = xx * ct + yy * st;
        double yt = -xx * st + yy * ct;
        traw[tid] = exp(-0.5 * (xt * xt + yt * yt)) * cos(2.0 * M_PI * 0.25 * xt);
    }
    __syncthreads();
    if (tid < 4) {
        double s = 0.0;
        for (int k = 0; k < 25; ++k) s += traw[tid * 25 + k];
        double mean = s / 25.0, ss = 0.0;
        for (int k = 0; k < 25; ++k) { double d = traw[tid * 25 + k] - mean; ss += d * d; }
        mean4[tid] = mean; nrm4[tid] = sqrt(ss) + 1e-8;
    }
    __syncthreads();
    if (tid < 100) g[tid] = (float)((traw[tid] - mean4[tid / 25]) / nrm4[tid / 25]);
    __syncthreads();

    // ---- Conv + per-block max (2 px/thread, no unroll: avoids R2 spill) ----
    int b   = blockIdx.x >> 5;           // NPB=32 blocks per batch
    int seg = blockIdx.x & 31;           // rows [seg*4, seg*4+4)
    const float* xb = x + b * 16384;     // x is (B,1,128,128)

    float v = 0.f;
#pragma unroll 1
    for (int k = 0; k < 2; ++k) {
        int pix = seg * 512 + k * 256 + tid;   // 512 pixels per block
        int i = pix >> 7, j = pix & 127;
        float val[25];
#pragma unroll
        for (int r = 0; r < 5; ++r) {
            int yi = i + r - 2;
            bool yok = (yi >= 0) & (yi <= 127);
            const float* xr = xb + yi * 128;
#pragma unroll
            for (int c = 0; c < 5; ++c) {
                int xj = j + c - 2;
                bool ok = yok & (xj >= 0) & (xj <= 127);
                val[r * 5 + c] = ok ? xr[xj] : 0.f;
            }
        }
#pragma unroll
        for (int o = 0; o < 4; ++o) {
            float sum = 0.f;
            const float* go = g + o * 25;
#pragma unroll
            for (int t = 0; t < 25; ++t) sum = fmaf(go[t], val[t], sum);
            v = fmaxf(v, fabsf(sum));
        }
    }
    for (int off = 32; off >= 1; off >>= 1) v = fmaxf(v, __shfl_xor(v, off));
    if ((tid & 63) == 0) wmax[tid >> 6] = v;
    __syncthreads();

    // ---- Publish per-batch max (signed-int fetch_max RMW) + take a ticket ----
    if (tid == 0) {
        float m = fmaxf(fmaxf(wmax[0], wmax[1]), fmaxf(wmax[2], wmax[3]));
        // non-negative float bits compare correctly as signed int; poison (neg) loses
        __hip_atomic_fetch_max(&bmax[b], (int)__float_as_uint(m),
                               __ATOMIC_RELAXED, __HIP_MEMORY_SCOPE_AGENT);
        unsigned old = __hip_atomic_fetch_add(cnt, 1u,
                               __ATOMIC_ACQ_REL, __HIP_MEMORY_SCOPE_AGENT);
        isLast = (old == GRID - 1u);     // cnt memset to 0 each call -> true last
    }
    __syncthreads();
    if (!isLast) return;

    // ---- True-last block: CAS-read 32 per-batch maxima -> global max -> counts ----
    if (tid < NB) {
        int exp = 0x7f800001;            // NaN bits: never produced by the conv
        __hip_atomic_compare_exchange_strong(&bmax[tid], &exp, exp,
                               __ATOMIC_ACQ_REL, __ATOMIC_ACQUIRE,
                               __HIP_MEMORY_SCOPE_AGENT);
        float bv = __uint_as_float((unsigned)exp);   // coherence-point value
        float m = bv;
        for (int off = 16; off >= 1; off >>= 1) m = fmaxf(m, __shfl_xor(m, off));
        int T = *Tin;
        float c1 = bv / (m + 1e-8f);
        float cc = fminf(fmaxf(c1, 0.f), 1.f);
        int cntv = 0;
        if (c1 > 0.01f) {
            int lat = (int)((1.0f - cc) * (float)(T - 1));  // trunc = astype(int32)
            if (lat < 0) lat = 0;
            if (lat > T - 1) lat = T - 1;
            cntv = T - lat;
        }
        out[tid] = 0.0f;                                    // preds: all-tie -> 0
        for (int c = 0; c < nC; ++c) out[NB + tid * nC + c] = (float)cntv;
    }
}

extern "C" void kernel_launch(void* const* d_in, const int* in_sizes, int n_in,
                              void* d_out, int out_size, void* d_ws, size_t ws_size,
                              hipStream_t stream) {
    const float* x  = (const float*)d_in[0];
    // d_in[1] (weights) provably does not affect the output: all weights > 0.
    const int*   Tp = (const int*)d_in[2];
    float* out = (float*)d_out;

    int*      bmax = (int*)d_ws;              // NB per-batch maxima (float bits)
    unsigned* cnt  = (unsigned*)(bmax + NB);  // ticket counter

    // Zero the ticket each call (memset node; graph-capturable). bmax needs no
    // init: publishes are signed-int max, poison/old values are <= real values.
    hipMemsetAsync(cnt, 0, sizeof(unsigned), stream);
    hipLaunchKernelGGL(fused_kernel, dim3(GRID), dim3(256), 0, stream,
                       x, bmax, cnt, Tp, out, 10);
}

// Round 8
// 16.178 us; speedup vs baseline: 2.1971x; 2.1971x over previous
//
#include <hip/hip_runtime.h>
#include <math.h>

// MozafariV3 forward collapses analytically:
//   counts[b, c] = (c1max_b > 0.01) ? T - clip(trunc((1 - c1max_b) * (T-1)), 0, T-1) : 0
//   with c1max_b = max_pixels|gabor_conv(x_b)| / (global_max + 1e-8)
//   preds[b] = argmax_c counts[b, :] = 0 (all classes tie; argmax picks first).
//
// R1: per-wave atomicMax onto 32 words serialized (314 us) — RMW coherence OK.
// R2: full unroll -> 256 VGPR -> 106 MB scratch spill (60 us).
// R3: stale seg*1024 base -> half image unscanned.
// R4: two kernels, 16.4 us, launch-bound. PROVEN fallback.
// R5/R6: fused+ticket FAILED: poisoned ticket selects non-last block; relaxed /
//        idempotent-RMW reads fold to plain atomic loads (stale cross-XCD).
// R7: fused+memset PASSED but 35.5 us — in-graph fillBuffer node costs ~39 us/replay.
//     Proven: fetch_max/exchange RMW publish + CAS read are cross-XCD coherent.
// R8: producer/consumer, init-independent. Workers exchange block-max into private
//     slots; block 0 CAS-polls until slots hold VALID bits (positive finite float).
//     Zeros, 0xAA poison, and the 0x80000000 sentinel (left for the next call) are
//     all invalid -> per-call completion detectable with no initialized state, no
//     memset, no ticket. Single dispatch.

#define NPB 32   // worker blocks per batch; each covers 4 rows (512 pixels)
#define NB  32   // batch
#define NWORK (NB * NPB)      // 1024 worker blocks
#define SENT 0x80000000u      // "consumed" sentinel (negative -> invalid)

__device__ __forceinline__ bool valid_bits(unsigned u) {
    return (u > 0u) & (u < 0x7f800000u);   // positive, finite, non-zero float
}

__global__ __launch_bounds__(256) void fused_kernel(const float* __restrict__ x,
                                                    unsigned* __restrict__ pb,   // NWORK slots
                                                    const int* __restrict__ Tin,
                                                    float* __restrict__ out,
                                                    int nC) {
    int tid = threadIdx.x;

    if (blockIdx.x == 0) {
        // ---------------- spinner / finalizer ----------------
        __shared__ float bm[NB];
        int b = tid >> 3, q = tid & 7;      // 8 threads per batch, 4 slots each
        float pv = 0.f;
#pragma unroll
        for (int k = 0; k < 4; ++k) {
            int idx = b * 32 + q * 4 + k;
            unsigned u;
            do {
                int e = 0x7f800001;          // impossible bits: CAS never succeeds on real data
                __hip_atomic_compare_exchange_strong((int*)&pb[idx], &e, e,
                        __ATOMIC_RELAXED, __ATOMIC_RELAXED, __HIP_MEMORY_SCOPE_AGENT);
                u = (unsigned)e;             // coherence-point value of the slot
            } while (!valid_bits(u));
            pv = fmaxf(pv, __uint_as_float(u));
        }
        // consume: sentinel my slots for the next call (this thread already read them)
#pragma unroll
        for (int k = 0; k < 4; ++k) {
            int idx = b * 32 + q * 4 + k;
            __hip_atomic_exchange((int*)&pb[idx], (int)SENT,
                                  __ATOMIC_RELAXED, __HIP_MEMORY_SCOPE_AGENT);
        }
        // 8-lane group reduce -> per-batch max
        for (int off = 4; off >= 1; off >>= 1) pv = fmaxf(pv, __shfl_xor(pv, off));
        if (q == 0) bm[b] = pv;
        __syncthreads();
        if (tid < NB) {
            float bv = bm[tid];
            float m = bv;
            for (int off = 16; off >= 1; off >>= 1) m = fmaxf(m, __shfl_xor(m, off));
            int T = *Tin;
            float c1 = bv / (m + 1e-8f);
            float cc = fminf(fmaxf(c1, 0.f), 1.f);
            int cntv = 0;
            if (c1 > 0.01f) {
                int lat = (int)((1.0f - cc) * (float)(T - 1));  // trunc = astype(int32)
                if (lat < 0) lat = 0;
                if (lat > T - 1) lat = T - 1;
                cntv = T - lat;
            }
            out[tid] = 0.0f;                                    // preds: all-class tie -> 0
            for (int c = 0; c < nC; ++c) out[NB + tid * nC + c] = (float)cntv;
        }
        return;
    }

    // ---------------- workers ----------------
    __shared__ float g[100];
    __shared__ double traw[100];
    __shared__ double mean4[4], nrm4[4];
    __shared__ float wmax[4];

    // Gabor build (double precision; proven absmax 0)
    if (tid < 100) {
        int o = tid / 25, t = tid % 25, r = t / 5, c = t % 5;
        double theta = (double)o * M_PI / 4.0;
        double ct = cos(theta), st = sin(theta);
        double xx = (double)(c - 2), yy = (double)(r - 2);
        double xt = xx * ct + yy * st;
        double yt = -xx * st + yy * ct;
        traw[tid] = exp(-0.5 * (xt * xt + yt * yt)) * cos(2.0 * M_PI * 0.25 * xt);
    }
    __syncthreads();
    if (tid < 4) {
        double s = 0.0;
        for (int k = 0; k < 25; ++k) s += traw[tid * 25 + k];
        double mean = s / 25.0, ss = 0.0;
        for (int k = 0; k < 25; ++k) { double d = traw[tid * 25 + k] - mean; ss += d * d; }
        mean4[tid] = mean; nrm4[tid] = sqrt(ss) + 1e-8;
    }
    __syncthreads();
    if (tid < 100) g[tid] = (float)((traw[tid] - mean4[tid / 25]) / nrm4[tid / 25]);
    __syncthreads();

    int w   = blockIdx.x - 1;            // worker index 0..1023
    int b   = w >> 5;                    // batch
    int seg = w & 31;                    // rows [seg*4, seg*4+4)
    const float* xb = x + b * 16384;     // x is (B,1,128,128)

    float v = 0.f;
#pragma unroll 1
    for (int k = 0; k < 2; ++k) {        // 2 px/thread; DO NOT full-unroll (R2 spill)
        int pix = seg * 512 + k * 256 + tid;
        int i = pix >> 7, j = pix & 127;
        float val[25];
#pragma unroll
        for (int r = 0; r < 5; ++r) {
            int yi = i + r - 2;
            bool yok = (yi >= 0) & (yi <= 127);
            const float* xr = xb + yi * 128;
#pragma unroll
            for (int c = 0; c < 5; ++c) {
                int xj = j + c - 2;
                bool ok = yok & (xj >= 0) & (xj <= 127);
                val[r * 5 + c] = ok ? xr[xj] : 0.f;
            }
        }
#pragma unroll
        for (int o = 0; o < 4; ++o) {
            float sum = 0.f;
            const float* go = g + o * 25;
#pragma unroll
            for (int t = 0; t < 25; ++t) sum = fmaf(go[t], val[t], sum);
            v = fmaxf(v, fabsf(sum));
        }
    }
    for (int off = 32; off >= 1; off >>= 1) v = fmaxf(v, __shfl_xor(v, off));
    if ((tid & 63) == 0) wmax[tid >> 6] = v;
    __syncthreads();

    // publish block max into private slot (RMW -> coherence point)
    if (tid == 0) {
        float m = fmaxf(fmaxf(wmax[0], wmax[1]), fmaxf(wmax[2], wmax[3]));
        __hip_atomic_exchange((int*)&pb[w], (int)__float_as_uint(m),
                              __ATOMIC_RELAXED, __HIP_MEMORY_SCOPE_AGENT);
    }
}

extern "C" void kernel_launch(void* const* d_in, const int* in_sizes, int n_in,
                              void* d_out, int out_size, void* d_ws, size_t ws_size,
                              hipStream_t stream) {
    const float* x  = (const float*)d_in[0];
    // d_in[1] (weights) provably does not affect the output: all weights > 0.
    const int*   Tp = (const int*)d_in[2];
    float* out = (float*)d_out;

    unsigned* pb = (unsigned*)d_ws;   // NWORK publish slots (float bits / sentinel)

    hipLaunchKernelGGL(fused_kernel, dim3(1 + NWORK), dim3(256), 0, stream,
                       x, pb, Tp, out, 10);
}

// Round 9
// 15.025 us; speedup vs baseline: 2.3657x; 1.0767x over previous
//
#include <hip/hip_runtime.h>
#include <math.h>

// MozafariV3 forward collapses analytically:
//   counts[b, c] = (c1max_b > 0.01) ? T - clip(trunc((1 - c1max_b) * (T-1)), 0, T-1) : 0
//   with c1max_b = max_pixels|gabor_conv(x_b)| / (global_max + 1e-8)
//   preds[b] = argmax_c counts[b, :] = 0 (all classes tie; argmax picks first).
//
// R1: per-wave atomicMax onto 32 words serialized (314 us) — RMW coherence OK.
// R2: full unroll -> 256 VGPR -> 106 MB scratch spill (60 us).
// R3: stale seg*1024 base -> half image unscanned.
// R4: two kernels, 16.4 us, launch-bound fallback.
// R5/R6: ticket+load FAILED (poisoned ticket; idempotent RMW folds to load).
// R7: memset ticket PASSED, 35.5 us — in-graph fill node costs ~39 us. Never again.
// R8: producer/consumer single dispatch, 16.2 us. Dispatch count is NOT the cost:
//     R4->R8 saved 0.2 us. Remaining: fp64 gabor per block, serial CAS tail.
// R9: float gabor (__expf/__cosf), parallel 4-slot CAS poll, s_sleep backoff.
//     Same init-independent slot protocol: valid = positive finite float bits;
//     zeros / 0xAA poison / 0x80000000 sentinel all invalid.

#define NPB 32   // worker blocks per batch; each covers 4 rows (512 pixels)
#define NB  32   // batch
#define NWORK (NB * NPB)      // 1024 worker blocks
#define SENT 0x80000000u      // "consumed" sentinel (negative -> invalid)

__device__ __forceinline__ bool valid_bits(unsigned u) {
    return (u > 0u) & (u < 0x7f800000u);   // positive, finite, non-zero float
}

__global__ __launch_bounds__(256) void fused_kernel(const float* __restrict__ x,
                                                    unsigned* __restrict__ pb,   // NWORK slots
                                                    const int* __restrict__ Tin,
                                                    float* __restrict__ out,
                                                    int nC) {
    int tid = threadIdx.x;

    if (blockIdx.x == 0) {
        // ---------------- spinner / finalizer ----------------
        __shared__ float bm[NB];
        int b = tid >> 3, q = tid & 7;      // 8 threads per batch, 4 slots each
        float pv = 0.f;
        unsigned got = 0u;
        while (got != 0xFu) {
#pragma unroll
            for (int k = 0; k < 4; ++k) {
                if (!(got & (1u << k))) {
                    int e = 0x7f800001;      // impossible bits: CAS never succeeds
                    __hip_atomic_compare_exchange_strong((int*)&pb[b * 32 + q * 4 + k],
                            &e, e, __ATOMIC_RELAXED, __ATOMIC_RELAXED,
                            __HIP_MEMORY_SCOPE_AGENT);
                    unsigned u = (unsigned)e;          // coherence-point value
                    if (valid_bits(u)) { pv = fmaxf(pv, __uint_as_float(u)); got |= 1u << k; }
                }
            }
            if (got != 0xFu) __builtin_amdgcn_s_sleep(2);   // back off ~128 cyc
        }
        // consume: sentinel my slots for the next call
#pragma unroll
        for (int k = 0; k < 4; ++k)
            __hip_atomic_exchange((int*)&pb[b * 32 + q * 4 + k], (int)SENT,
                                  __ATOMIC_RELAXED, __HIP_MEMORY_SCOPE_AGENT);
        // 8-lane group reduce -> per-batch max
        for (int off = 4; off >= 1; off >>= 1) pv = fmaxf(pv, __shfl_xor(pv, off));
        if (q == 0) bm[b] = pv;
        __syncthreads();
        if (tid < NB) {
            float bv = bm[tid];
            float m = bv;
            for (int off = 16; off >= 1; off >>= 1) m = fmaxf(m, __shfl_xor(m, off));
            int T = *Tin;
            float c1 = bv / (m + 1e-8f);
            float cc = fminf(fmaxf(c1, 0.f), 1.f);
            int cntv = 0;
            if (c1 > 0.01f) {
                int lat = (int)((1.0f - cc) * (float)(T - 1));  // trunc = astype(int32)
                if (lat < 0) lat = 0;
                if (lat > T - 1) lat = T - 1;
                cntv = T - lat;
            }
            out[tid] = 0.0f;                                    // preds: all-class tie -> 0
            for (int c = 0; c < nC; ++c) out[NB + tid * nC + c] = (float)cntv;
        }
        return;
    }

    // ---------------- workers ----------------
    __shared__ float g[100];
    __shared__ float mean4[4], nrm4[4];
    __shared__ float wmax[4];

    // Gabor build in float (__expf/__cosf): ~1e-6 rel shift; c1 is a ratio of two
    // shifted-together maxima, so integer lat boundaries (spacing ~0.07) are safe.
    if (tid < 100) {
        int o = tid / 25, t = tid % 25, r = t / 5, c = t % 5;
        float theta = (float)o * (float)M_PI * 0.25f;
        float ct = __cosf(theta), st = __sinf(theta);
        float xx = (float)(c - 2), yy = (float)(r - 2);
        float xt = xx * ct + yy * st;
        float yt = -xx * st + yy * ct;
        g[tid] = __expf(-0.5f * (xt * xt + yt * yt)) * __cosf((float)(2.0 * M_PI * 0.25) * xt);
    }
    __syncthreads();
    if (tid < 4) {
        float s = 0.f;
        for (int k = 0; k < 25; ++k) s += g[tid * 25 + k];
        float mean = s * (1.f / 25.f), ss = 0.f;
        for (int k = 0; k < 25; ++k) { float d = g[tid * 25 + k] - mean; ss += d * d; }
        mean4[tid] = mean; nrm4[tid] = __fsqrt_rn(ss) + 1e-8f;
    }
    __syncthreads();
    if (tid < 100) g[tid] = (g[tid] - mean4[tid / 25]) / nrm4[tid / 25];
    __syncthreads();

    int w   = blockIdx.x - 1;            // worker index 0..1023
    int b   = w >> 5;                    // batch
    int seg = w & 31;                    // rows [seg*4, seg*4+4)
    const float* xb = x + b * 16384;     // x is (B,1,128,128)

    float v = 0.f;
#pragma unroll 1
    for (int k = 0; k < 2; ++k) {        // 2 px/thread; DO NOT full-unroll (R2 spill)
        int pix = seg * 512 + k * 256 + tid;
        int i = pix >> 7, j = pix & 127;
        float val[25];
#pragma unroll
        for (int r = 0; r < 5; ++r) {
            int yi = i + r - 2;
            bool yok = (yi >= 0) & (yi <= 127);
            const float* xr = xb + yi * 128;
#pragma unroll
            for (int c = 0; c < 5; ++c) {
                int xj = j + c - 2;
                bool ok = yok & (xj >= 0) & (xj <= 127);
                val[r * 5 + c] = ok ? xr[xj] : 0.f;
            }
        }
#pragma unroll
        for (int o = 0; o < 4; ++o) {
            float sum = 0.f;
            const float* go = g + o * 25;
#pragma unroll
            for (int t = 0; t < 25; ++t) sum = fmaf(go[t], val[t], sum);
            v = fmaxf(v, fabsf(sum));
        }
    }
    for (int off = 32; off >= 1; off >>= 1) v = fmaxf(v, __shfl_xor(v, off));
    if ((tid & 63) == 0) wmax[tid >> 6] = v;
    __syncthreads();

    // publish block max into private slot (RMW -> coherence point)
    if (tid == 0) {
        float m = fmaxf(fmaxf(wmax[0], wmax[1]), fmaxf(wmax[2], wmax[3]));
        __hip_atomic_exchange((int*)&pb[w], (int)__float_as_uint(m),
                              __ATOMIC_RELAXED, __HIP_MEMORY_SCOPE_AGENT);
    }
}

extern "C" void kernel_launch(void* const* d_in, const int* in_sizes, int n_in,
                              void* d_out, int out_size, void* d_ws, size_t ws_size,
                              hipStream_t stream) {
    const float* x  = (const float*)d_in[0];
    // d_in[1] (weights) provably does not affect the output: all weights > 0.
    const int*   Tp = (const int*)d_in[2];
    float* out = (float*)d_out;

    unsigned* pb = (unsigned*)d_ws;   // NWORK publish slots (float bits / sentinel)

    hipLaunchKernelGGL(fused_kernel, dim3(1 + NWORK), dim3(256), 0, stream,
                       x, pb, Tp, out, 10);
}

// Round 10
// 13.791 us; speedup vs baseline: 2.5773x; 1.0895x over previous
//
#include <hip/hip_runtime.h>
#include <math.h>

// MozafariV3 forward collapses analytically:
//   counts[b, c] = (c1max_b > 0.01) ? T - clip(trunc((1 - c1max_b) * (T-1)), 0, T-1) : 0
//   with c1max_b = max_pixels|gabor_conv(x_b)| / (global_max + 1e-8)
//   preds[b] = argmax_c counts[b, :] = 0 (all classes tie; argmax picks first).
//
// R1: per-wave atomicMax onto 32 words serialized (314 us) — RMW coherence OK.
// R2: full unroll of 8 INDEPENDENT windows -> 256 VGPR -> scratch spill (60 us).
// R3: stale pixel base -> half image unscanned.
// R4: two kernels, 16.4 us. R8: fused single dispatch 16.2 us (dispatch count ~free).
// R5/R6: ticket+load FAILED (poisoned ticket; idempotent RMW folds to load).
// R7: in-graph memset node costs ~39 us. Never put fill nodes in the graph.
// R9: float gabor + parallel CAS poll: 15.0 us.
// R10: geometry. 512 workers (halved ramp), 4 consecutive px/thread sharing ONE
//      5x8 window (40 loads + 400 FMA vs 100+400), spinner polls its 2 slots in
//      parallel (1 round-trip tail). Slot protocol unchanged (init-independent):
//      valid = positive finite float bits; 0 / 0xAA poison / sentinel invalid.

#define NB  32                 // batch
#define WPB 16                 // worker blocks per batch; each covers 8 rows (1024 px)
#define NWORK (NB * WPB)       // 512 worker blocks
#define SENT 0x80000000u       // "consumed" sentinel (negative -> invalid)

__device__ __forceinline__ bool valid_bits(unsigned u) {
    return (u > 0u) & (u < 0x7f800000u);   // positive, finite, non-zero float
}

__global__ __launch_bounds__(256) void fused_kernel(const float* __restrict__ x,
                                                    unsigned* __restrict__ pb,   // NWORK slots
                                                    const int* __restrict__ Tin,
                                                    float* __restrict__ out,
                                                    int nC) {
    int tid = threadIdx.x;

    if (blockIdx.x == 0) {
        // ---------------- spinner / finalizer ----------------
        __shared__ float bm[NB];
        int T = *Tin;                        // prefetch before the poll loop
        int s0 = tid * 2;                    // my two slots (same batch: s0 even)
        int b = tid >> 3, q = tid & 7;       // 8 threads per batch (16 slots)
        float pv = 0.f;
        unsigned got = 0u;
        while (got != 0x3u) {
#pragma unroll
            for (int k = 0; k < 2; ++k) {
                if (!(got & (1u << k))) {
                    int e = 0x7f800001;      // impossible bits: CAS never succeeds
                    __hip_atomic_compare_exchange_strong((int*)&pb[s0 + k],
                            &e, e, __ATOMIC_RELAXED, __ATOMIC_RELAXED,
                            __HIP_MEMORY_SCOPE_AGENT);
                    unsigned u = (unsigned)e;            // coherence-point value
                    if (valid_bits(u)) { pv = fmaxf(pv, __uint_as_float(u)); got |= 1u << k; }
                }
            }
            if (got != 0x3u) __builtin_amdgcn_s_sleep(2);   // back off ~128 cyc
        }
        // consume: sentinel my slots for the next call
#pragma unroll
        for (int k = 0; k < 2; ++k)
            __hip_atomic_exchange((int*)&pb[s0 + k], (int)SENT,
                                  __ATOMIC_RELAXED, __HIP_MEMORY_SCOPE_AGENT);
        // 8-lane group reduce -> per-batch max
        for (int off = 4; off >= 1; off >>= 1) pv = fmaxf(pv, __shfl_xor(pv, off));
        if (q == 0) bm[b] = pv;
        __syncthreads();
        if (tid < NB) {
            float bv = bm[tid];
            float m = bv;
            for (int off = 16; off >= 1; off >>= 1) m = fmaxf(m, __shfl_xor(m, off));
            float c1 = bv / (m + 1e-8f);
            float cc = fminf(fmaxf(c1, 0.f), 1.f);
            int cntv = 0;
            if (c1 > 0.01f) {
                int lat = (int)((1.0f - cc) * (float)(T - 1));  // trunc = astype(int32)
                if (lat < 0) lat = 0;
                if (lat > T - 1) lat = T - 1;
                cntv = T - lat;
            }
            out[tid] = 0.0f;                                    // preds: all-class tie -> 0
            for (int c = 0; c < nC; ++c) out[NB + tid * nC + c] = (float)cntv;
        }
        return;
    }

    // ---------------- workers ----------------
    __shared__ float g[100];
    __shared__ float mean4[4], nrm4[4];
    __shared__ float wmax[4];

    // Gabor build in float (__expf/__cosf): ~1e-6 rel shift; c1 is a ratio of two
    // shifted-together maxima, so integer lat boundaries (spacing ~0.07) are safe.
    if (tid < 100) {
        int o = tid / 25, t = tid % 25, r = t / 5, c = t % 5;
        float theta = (float)o * (float)M_PI * 0.25f;
        float ct = __cosf(theta), st = __sinf(theta);
        float xx = (float)(c - 2), yy = (float)(r - 2);
        float xt = xx * ct + yy * st;
        float yt = -xx * st + yy * ct;
        g[tid] = __expf(-0.5f * (xt * xt + yt * yt)) * __cosf((float)(2.0 * M_PI * 0.25) * xt);
    }
    __syncthreads();
    if (tid < 4) {
        float s = 0.f;
        for (int k = 0; k < 25; ++k) s += g[tid * 25 + k];
        float mean = s * (1.f / 25.f), ss = 0.f;
        for (int k = 0; k < 25; ++k) { float d = g[tid * 25 + k] - mean; ss += d * d; }
        mean4[tid] = mean; nrm4[tid] = __fsqrt_rn(ss) + 1e-8f;
    }
    __syncthreads();
    if (tid < 100) g[tid] = (g[tid] - mean4[tid / 25]) / nrm4[tid / 25];
    __syncthreads();

    int w   = blockIdx.x - 1;            // worker index 0..511
    int b   = w >> 4;                    // batch
    int seg = w & 15;                    // rows [seg*8, seg*8+8)
    const float* xb = x + b * 16384;     // x is (B,1,128,128)

    // 4 consecutive pixels per thread from ONE shared 5x8 window (single live
    // window array: no R2-style spill).
    int p = seg * 1024 + tid * 4;
    int i = p >> 7, j = p & 127;         // j in {0,4,...,124}
    float win[5][8];
#pragma unroll
    for (int r = 0; r < 5; ++r) {
        int yi = i + r - 2;
        bool yok = (yi >= 0) & (yi <= 127);
        const float* xr = xb + yi * 128;
#pragma unroll
        for (int c = 0; c < 8; ++c) {
            int xj = j + c - 2;
            bool ok = yok & (xj >= 0) & (xj <= 127);
            win[r][c] = ok ? xr[xj] : 0.f;
        }
    }
    float v = 0.f;
#pragma unroll
    for (int o = 0; o < 4; ++o) {
        const float* go = g + o * 25;
#pragma unroll
        for (int pxi = 0; pxi < 4; ++pxi) {
            float sum = 0.f;
#pragma unroll
            for (int r = 0; r < 5; ++r)
#pragma unroll
                for (int c = 0; c < 5; ++c)
                    sum = fmaf(go[r * 5 + c], win[r][pxi + c], sum);
            v = fmaxf(v, fabsf(sum));
        }
    }

    for (int off = 32; off >= 1; off >>= 1) v = fmaxf(v, __shfl_xor(v, off));
    if ((tid & 63) == 0) wmax[tid >> 6] = v;
    __syncthreads();

    // publish block max into private slot (RMW -> coherence point)
    if (tid == 0) {
        float m = fmaxf(fmaxf(wmax[0], wmax[1]), fmaxf(wmax[2], wmax[3]));
        __hip_atomic_exchange((int*)&pb[w], (int)__float_as_uint(m),
                              __ATOMIC_RELAXED, __HIP_MEMORY_SCOPE_AGENT);
    }
}

extern "C" void kernel_launch(void* const* d_in, const int* in_sizes, int n_in,
                              void* d_out, int out_size, void* d_ws, size_t ws_size,
                              hipStream_t stream) {
    const float* x  = (const float*)d_in[0];
    // d_in[1] (weights) provably does not affect the output: all weights > 0.
    const int*   Tp = (const int*)d_in[2];
    float* out = (float*)d_out;

    unsigned* pb = (unsigned*)d_ws;   // NWORK publish slots (float bits / sentinel)

    hipLaunchKernelGGL(fused_kernel, dim3(1 + NWORK), dim3(256), 0, stream,
                       x, pb, Tp, out, 10);
}

// Round 11
// 10.622 us; speedup vs baseline: 3.3464x; 1.2984x over previous
//
#include <hip/hip_runtime.h>
#include <math.h>

// MozafariV3 forward collapses analytically:
//   counts[b, c] = (c1max_b > 0.01) ? T - clip(trunc((1 - c1max_b) * (T-1)), 0, T-1) : 0
//   with c1max_b = max_pixels|gabor_conv(x_b)| / (global_max + 1e-8)
//   preds[b] = argmax_c counts[b, :] = 0 (all classes tie; argmax picks first).
//
// R1: per-wave atomicMax onto 32 words serialized (314 us) — RMW coherence OK.
// R2: 8 INDEPENDENT windows live at once -> 256 VGPR -> scratch spill (60 us).
// R3: stale pixel base -> half image unscanned.
// R4/R8: dispatch count is ~free (16.4 two-kernel vs 16.2 fused).
// R5/R6: ticket+load FAILED (poisoned ticket; idempotent RMW folds to load).
// R7: in-graph memset/fill node costs ~39 us. Never.
// R9: float gabor + parallel CAS poll: 15.0. R10: 512 workers, 4 px/thread shared
//     window: 13.8. (rocprof note: counter-replay showed one 30 ms fused dispatch —
//     spin protocol is profiling-hostile, timing path unaffected.)
// R11: 256 workers + spinner (257 blocks), 8 px/thread from ONE 5x16 window loaded
//      as 4 aligned float4 per row (20 load instrs / 800 FMA per thread); spinner
//      polls 1 slot/thread. Slot protocol unchanged (init-independent): valid =
//      positive finite float bits; 0 / 0xAA poison / 0x80000000 sentinel invalid.

#define NB  32                 // batch
#define WPB 8                  // worker blocks per batch; each covers 16 rows
#define NWORK (NB * WPB)       // 256 worker blocks
#define SENT 0x80000000u       // "consumed" sentinel (negative -> invalid)

__device__ __forceinline__ bool valid_bits(unsigned u) {
    return (u > 0u) & (u < 0x7f800000u);   // positive, finite, non-zero float
}

__global__ __launch_bounds__(256) void fused_kernel(const float* __restrict__ x,
                                                    unsigned* __restrict__ pb,   // NWORK slots
                                                    const int* __restrict__ Tin,
                                                    float* __restrict__ out,
                                                    int nC) {
    int tid = threadIdx.x;

    if (blockIdx.x == 0) {
        // ---------------- spinner / finalizer ----------------
        __shared__ float bm[NB];
        int T = *Tin;                        // prefetch before the poll loop
        int b = tid >> 3, q = tid & 7;       // 8 threads per batch, 1 slot each
        float pv = 0.f;
        for (;;) {
            int e = 0x7f800001;              // impossible bits: CAS never succeeds
            __hip_atomic_compare_exchange_strong((int*)&pb[tid], &e, e,
                    __ATOMIC_RELAXED, __ATOMIC_RELAXED, __HIP_MEMORY_SCOPE_AGENT);
            unsigned u = (unsigned)e;        // coherence-point value
            if (valid_bits(u)) { pv = __uint_as_float(u); break; }
            __builtin_amdgcn_s_sleep(2);     // back off ~128 cyc
        }
        // consume: sentinel my slot for the next call
        __hip_atomic_exchange((int*)&pb[tid], (int)SENT,
                              __ATOMIC_RELAXED, __HIP_MEMORY_SCOPE_AGENT);
        // 8-lane group reduce -> per-batch max
        for (int off = 4; off >= 1; off >>= 1) pv = fmaxf(pv, __shfl_xor(pv, off));
        if (q == 0) bm[b] = pv;
        __syncthreads();
        if (tid < NB) {
            float bv = bm[tid];
            float m = bv;
            for (int off = 16; off >= 1; off >>= 1) m = fmaxf(m, __shfl_xor(m, off));
            float c1 = bv / (m + 1e-8f);
            float cc = fminf(fmaxf(c1, 0.f), 1.f);
            int cntv = 0;
            if (c1 > 0.01f) {
                int lat = (int)((1.0f - cc) * (float)(T - 1));  // trunc = astype(int32)
                if (lat < 0) lat = 0;
                if (lat > T - 1) lat = T - 1;
                cntv = T - lat;
            }
            out[tid] = 0.0f;                                    // preds: all-class tie -> 0
            for (int c = 0; c < nC; ++c) out[NB + tid * nC + c] = (float)cntv;
        }
        return;
    }

    // ---------------- workers ----------------
    __shared__ float g[100];
    __shared__ float mean4[4], nrm4[4];
    __shared__ float wmax[4];

    // Gabor build in float (__expf/__cosf): ~1e-6 rel shift; c1 is a ratio of two
    // shifted-together maxima, so integer lat boundaries (spacing ~0.07) are safe.
    if (tid < 100) {
        int o = tid / 25, t = tid % 25, r = t / 5, c = t % 5;
        float theta = (float)o * (float)M_PI * 0.25f;
        float ct = __cosf(theta), st = __sinf(theta);
        float xx = (float)(c - 2), yy = (float)(r - 2);
        float xt = xx * ct + yy * st;
        float yt = -xx * st + yy * ct;
        g[tid] = __expf(-0.5f * (xt * xt + yt * yt)) * __cosf((float)(2.0 * M_PI * 0.25) * xt);
    }
    __syncthreads();
    if (tid < 4) {
        float s = 0.f;
        for (int k = 0; k < 25; ++k) s += g[tid * 25 + k];
        float mean = s * (1.f / 25.f), ss = 0.f;
        for (int k = 0; k < 25; ++k) { float d = g[tid * 25 + k] - mean; ss += d * d; }
        mean4[tid] = mean; nrm4[tid] = __fsqrt_rn(ss) + 1e-8f;
    }
    __syncthreads();
    if (tid < 100) g[tid] = (g[tid] - mean4[tid / 25]) / nrm4[tid / 25];
    __syncthreads();

    int w   = blockIdx.x - 1;            // worker index 0..255
    int b   = w >> 3;                    // batch
    int seg = w & 7;                     // rows [seg*16, seg*16+16)
    const float* xb = x + b * 16384;     // x is (B,1,128,128)

    // 8 consecutive pixels per thread from ONE 5x16 window (cols [j-4, j+12)),
    // loaded as 4 aligned float4 per row (j % 8 == 0 -> j-4 is 16B aligned).
    int base = seg * 2048 + tid * 8;
    int i = base >> 7, j = base & 127;   // j in {0,8,...,120}
    float win[5][16];
#pragma unroll
    for (int r = 0; r < 5; ++r) {
        int yi = i + r - 2;
        bool yok = (yi >= 0) & (yi <= 127);
        const float* xr = xb + yi * 128;
#pragma unroll
        for (int q4 = 0; q4 < 4; ++q4) {
            int col = j - 4 + q4 * 4;
            bool ok = yok & (col >= 0) & (col <= 124);
            float4 f = ok ? *reinterpret_cast<const float4*>(xr + col)
                          : make_float4(0.f, 0.f, 0.f, 0.f);
            win[r][q4 * 4 + 0] = f.x; win[r][q4 * 4 + 1] = f.y;
            win[r][q4 * 4 + 2] = f.z; win[r][q4 * 4 + 3] = f.w;
        }
    }
    float v = 0.f;
#pragma unroll
    for (int o = 0; o < 4; ++o) {
        const float* go = g + o * 25;
#pragma unroll
        for (int px = 0; px < 8; ++px) {
            float sum = 0.f;
#pragma unroll
            for (int r = 0; r < 5; ++r)
#pragma unroll
                for (int c = 0; c < 5; ++c)
                    sum = fmaf(go[r * 5 + c], win[r][px + c + 2], sum);
            v = fmaxf(v, fabsf(sum));
        }
    }

    for (int off = 32; off >= 1; off >>= 1) v = fmaxf(v, __shfl_xor(v, off));
    if ((tid & 63) == 0) wmax[tid >> 6] = v;
    __syncthreads();

    // publish block max into private slot (RMW -> coherence point)
    if (tid == 0) {
        float m = fmaxf(fmaxf(wmax[0], wmax[1]), fmaxf(wmax[2], wmax[3]));
        __hip_atomic_exchange((int*)&pb[w], (int)__float_as_uint(m),
                              __ATOMIC_RELAXED, __HIP_MEMORY_SCOPE_AGENT);
    }
}

extern "C" void kernel_launch(void* const* d_in, const int* in_sizes, int n_in,
                              void* d_out, int out_size, void* d_ws, size_t ws_size,
                              hipStream_t stream) {
    const float* x  = (const float*)d_in[0];
    // d_in[1] (weights) provably does not affect the output: all weights > 0.
    const int*   Tp = (const int*)d_in[2];
    float* out = (float*)d_out;

    unsigned* pb = (unsigned*)d_ws;   // NWORK publish slots (float bits / sentinel)

    hipLaunchKernelGGL(fused_kernel, dim3(1 + NWORK), dim3(256), 0, stream,
                       x, pb, Tp, out, 10);
}